// Round 4
// baseline (5905.169 us; speedup 1.0000x reference)
//
#include <hip/hip_runtime.h>
#include <hip/hip_bf16.h>
#include <stdint.h>

// StackedContextViT forward, MI355X gfx950. ALL inputs/outputs are FLOAT32.
// Internal: bf16 storage for activations + MFMA bf16 compute, f32 accumulate,
// f32 epilogue math, matrix weights converted f32->bf16 into ws staging.
// B=4 N=1024 PD=768 D=768 H=12 HD=64 L=6 F=3072 V=1024 G=32
// d_ws layout: [0]mode | [256] X bf16[4096,768] (6MB) | WA bf16 (4.72MB) |
//              WB2 bf16 (4.72MB) | S bf16 [CH,1024,1024] (CH*2MB, CH in [1,12])
// d_out (f32, 16.79MB) doubles as bf16 scratch until the final head GEMM:
//   per batch: QK[1024,1536] | VT[768,1024] | O[1024,768] | XR[1024,768]  (u16)
//   per chunk: HB[1024,3072] | XR[1024,768]                               (u16)

#define BM 128
#define BN 128
#define BK 32

using u16 = unsigned short;
typedef __attribute__((ext_vector_type(8))) short short8;
typedef __attribute__((ext_vector_type(4))) float f32x4;

#define GPTR(p) ((const __attribute__((address_space(1))) void*)(p))
#define LPTR(p) ((__attribute__((address_space(3))) void*)(p))

__device__ __forceinline__ float b2f(u16 u){
  union { unsigned int i; float f; } x; x.i = ((unsigned int)u) << 16; return x.f;
}
// NaN-scrub + clamp, then RNE f32->bf16
__device__ __forceinline__ u16 f2b(float f){
  f = fminf(fmaxf(f, -448.0f), 448.0f);
  union { float f; unsigned int i; } x; x.f = f;
  unsigned int r = x.i + 0x7FFFu + ((x.i >> 16) & 1u);
  return (u16)(r >> 16);
}

// ---- mask dtype detection: 0=u8 bool, 1=bf16, 2=f32, 3=i32 ----
__global__ __launch_bounds__(256) void detect_k(const u16* __restrict__ mk, int* __restrict__ mode){
  __shared__ int f[3];
  int tid = threadIdx.x;
  if (tid < 3) f[tid] = 0;
  __syncthreads();
  for (int i = tid; i < 2048; i += 256){
    u16 u = mk[i];
    if (u == 256 || u == 257) atomicOr(&f[0], 1);
    if (u == 0x3F80){ if ((i & 1) == 0) atomicOr(&f[1], 1); else atomicOr(&f[2], 1); }
  }
  __syncthreads();
  if (tid == 0){
    int m;
    if (f[0]) m = 0;
    else if (f[1]) m = 1;
    else if (f[2]) m = 2;
    else m = 3;
    *mode = m;
  }
}

__device__ __forceinline__ bool mask_at(const void* mk, int mode, int i){
  if (mode == 0) return ((const unsigned char*)mk)[i] != 0;
  if (mode == 1) return ((const u16*)mk)[i] != 0;
  if (mode == 2) return ((const float*)mk)[i] != 0.0f;
  return ((const int*)mk)[i] != 0;
}

// ---- f32 weight -> bf16 staging, 4 elems/thread ----
__global__ __launch_bounds__(256) void wconv_k(const float* __restrict__ src, u16* __restrict__ dst){
  long i = ((long)blockIdx.x * 256 + threadIdx.x) * 4;
  float4 v = *(const float4*)(src + i);
  dst[i]     = f2b(v.x);
  dst[i + 1] = f2b(v.y);
  dst[i + 2] = f2b(v.z);
  dst[i + 3] = f2b(v.w);
}

// ---- masked-patch select + f32->bf16, one 1024-row chunk ----
__global__ __launch_bounds__(256) void embed_k(const float* __restrict__ patches, const void* __restrict__ mask,
                                               const int* __restrict__ mode, const float* __restrict__ mtok,
                                               u16* __restrict__ MP, int row0){
  int row = blockIdx.x;                          // [0,1024)
  bool m = mask_at(mask, *mode, row0 + row);
  int tid = threadIdx.x;
  long base = (long)row * 768;
  #pragma unroll
  for (int i = 0; i < 3; i++){
    int p = tid + i * 256;
    MP[base + p] = f2b(m ? mtok[p] : patches[base + p]);
  }
}

// ---- mask echo (output #2, f32 0/1) ----
__global__ __launch_bounds__(256) void maskout_k(const void* __restrict__ mask, const int* __restrict__ mode,
                                                 float* __restrict__ out){
  int i = blockIdx.x * 256 + threadIdx.x;        // 4096
  out[i] = mask_at(mask, *mode, i) ? 1.0f : 0.0f;
}

// ---- layernorm over D=768 (bf16 in/out, f32 params+math), 1024 rows ----
__global__ __launch_bounds__(256) void ln_k(const u16* __restrict__ XR, u16* __restrict__ X,
                                            const float* __restrict__ s, const float* __restrict__ b){
  int row = blockIdx.x;
  int tid = threadIdx.x;
  const u16* xr = XR + (long)row * 768;
  float v0 = b2f(xr[tid]), v1 = b2f(xr[tid + 256]), v2 = b2f(xr[tid + 512]);
  float sum = v0 + v1 + v2, sq = v0 * v0 + v1 * v1 + v2 * v2;
  #pragma unroll
  for (int off = 32; off; off >>= 1){ sum += __shfl_xor(sum, off); sq += __shfl_xor(sq, off); }
  __shared__ float ls[4], lq[4];
  int wave = tid >> 6, lane = tid & 63;
  if (lane == 0){ ls[wave] = sum; lq[wave] = sq; }
  __syncthreads();
  sum = ls[0] + ls[1] + ls[2] + ls[3];
  sq  = lq[0] + lq[1] + lq[2] + lq[3];
  float mu = sum * (1.0f / 768.0f);
  float var = fmaxf(sq * (1.0f / 768.0f) - mu * mu, 0.0f);
  float rs = rsqrtf(var + 1e-5f);
  u16* xo = X + (long)row * 768;
  xo[tid]       = f2b((v0 - mu) * rs * s[tid]       + b[tid]);
  xo[tid + 256] = f2b((v1 - mu) * rs * s[tid + 256] + b[tid + 256]);
  xo[tid + 512] = f2b((v2 - mu) * rs * s[tid + 512] + b[tid + 512]);
}

// ---- softmax over rows of 1024 (in place, bf16), one wave per row ----
__global__ __launch_bounds__(256) void softmax_k(u16* __restrict__ S){
  long row = (long)blockIdx.x * 4 + (threadIdx.x >> 6);
  u16* p = S + row * 1024;
  int lane = threadIdx.x & 63;
  float v[16]; float mx = -1e30f;
  #pragma unroll
  for (int i = 0; i < 16; i++){ v[i] = b2f(p[lane + i * 64]); mx = fmaxf(mx, v[i]); }
  #pragma unroll
  for (int off = 32; off; off >>= 1) mx = fmaxf(mx, __shfl_xor(mx, off));
  float sum = 0.0f;
  #pragma unroll
  for (int i = 0; i < 16; i++){ v[i] = __expf(v[i] - mx); sum += v[i]; }
  #pragma unroll
  for (int off = 32; off; off >>= 1) sum += __shfl_xor(sum, off);
  float inv = 1.0f / sum;
  #pragma unroll
  for (int i = 0; i < 16; i++) p[lane + i * 64] = f2b(v[i] * inv);
}

// ---- generic bf16 MFMA GEMM: C = A[.,K] * W[N,K]^T (+ epilogue) ----
// EPI: 0=qkv (QK natural ldc=1536, V -> VT), 1=scores(*scale + f32 rel bias),
//      2=pv, 3=bias+resid, 4=bias+gelu, 5=bias -> f32 out, 6=bias+posemb
struct GP {
  const u16* A; const u16* W; u16* C; float* Cf;
  const float* bias; const float* relb; const float* pose;
  const u16* resid;
  u16* Cv;
  long sAz, sWz, sCz;
  int lda, ldw, ldc;
  int N, K;
  int wclamp, zBase;
  float scale;
};

template<int EPI>
__global__ __launch_bounds__(256)
void gemm_k(GP g){
  __shared__ __align__(16) u16 As[BM * BK];
  __shared__ __align__(16) u16 Bs[BN * BK];
  const int tid  = threadIdx.x;
  const int wave = tid >> 6, lane = tid & 63;
  const int quad = lane >> 4, l16 = lane & 15;
  const int wm = wave >> 1, wn = wave & 1;
  const int m0 = blockIdx.y * BM, n0 = blockIdx.x * BN;
  const int z = blockIdx.z;
  const u16* Ab = g.A + (long)z * g.sAz;
  const u16* Wb = g.W + (long)z * g.sWz;

  f32x4 acc[4][4];
  #pragma unroll
  for (int i = 0; i < 4; i++)
    #pragma unroll
    for (int j = 0; j < 4; j++) acc[i][j] = (f32x4){0.f, 0.f, 0.f, 0.f};

  const int c0 = wave * 64 + lane;
  const int c1 = c0 + 256;
  const u16* a0 = Ab + (long)(m0 + (c0 >> 2)) * g.lda + (c0 & 3) * 8;
  const u16* a1 = Ab + (long)(m0 + (c1 >> 2)) * g.lda + (c1 & 3) * 8;
  const u16* w0 = Wb + (long)min(n0 + (c0 >> 2), g.wclamp) * g.ldw + (c0 & 3) * 8;
  const u16* w1 = Wb + (long)min(n0 + (c1 >> 2), g.wclamp) * g.ldw + (c1 & 3) * 8;
  u16* asb0 = As + (wave * 64) * 8;
  u16* asb1 = As + (256 + wave * 64) * 8;
  u16* bsb0 = Bs + (wave * 64) * 8;
  u16* bsb1 = Bs + (256 + wave * 64) * 8;

  for (int kt = 0; kt < g.K; kt += BK){
    __builtin_amdgcn_global_load_lds(GPTR(a0 + kt), LPTR(asb0), 16, 0, 0);
    __builtin_amdgcn_global_load_lds(GPTR(a1 + kt), LPTR(asb1), 16, 0, 0);
    __builtin_amdgcn_global_load_lds(GPTR(w0 + kt), LPTR(bsb0), 16, 0, 0);
    __builtin_amdgcn_global_load_lds(GPTR(w1 + kt), LPTR(bsb1), 16, 0, 0);
    __syncthreads();
    short8 af[4], bf[4];
    #pragma unroll
    for (int i = 0; i < 4; i++){
      af[i] = *(const short8*)&As[(wm * 64 + i * 16 + l16) * BK + quad * 8];
      bf[i] = *(const short8*)&Bs[(wn * 64 + i * 16 + l16) * BK + quad * 8];
    }
    #pragma unroll
    for (int i = 0; i < 4; i++)
      #pragma unroll
      for (int j = 0; j < 4; j++)
        acc[i][j] = __builtin_amdgcn_mfma_f32_16x16x32_bf16(af[i], bf[j], acc[i][j], 0, 0, 0);
    __syncthreads();
  }

  // epilogue: C/D layout col=lane&15, row=quad*4+reg
  #pragma unroll
  for (int i = 0; i < 4; i++){
    #pragma unroll
    for (int j = 0; j < 4; j++){
      #pragma unroll
      for (int rr = 0; rr < 4; rr++){
        const long r = (long)m0 + wm * 64 + i * 16 + quad * 4 + rr;
        const int  c = n0 + wn * 64 + j * 16 + l16;
        if (c >= g.N) continue;
        float v = acc[i][j][rr];
        if constexpr (EPI == 0){            // qkv: QK natural, V transposed
          u16 o = f2b(v + g.bias[c]);
          if (c < 1536) g.C[r * 1536 + c] = o;
          else          g.Cv[(long)(c - 1536) * 1024 + r] = o;   // VT[h*64+hd][n]
        } else if constexpr (EPI == 1){     // scores: *scale + f32 Swin rel-bias
          const int rq = (int)r;
          const int ir = (rq >> 5) - (c >> 5) + 31;
          const int ic = (rq & 31) - (c & 31) + 31;
          float val = v * g.scale + g.relb[ir * 63 + ic];
          (g.C + (long)z * g.sCz)[(long)rq * 1024 + c] = f2b(val);
        } else if constexpr (EPI == 2){     // pv -> O[n][head*64+hd]
          g.C[r * 768 + (g.zBase + z) * 64 + c] = f2b(v);
        } else if constexpr (EPI == 3){     // bias + residual
          long o = r * (long)g.ldc + c;
          g.C[o] = f2b(v + g.bias[c] + b2f(g.resid[o]));
        } else if constexpr (EPI == 4){     // bias + exact gelu
          float t = v + g.bias[c];
          g.C[r * (long)g.ldc + c] = f2b(0.5f * t * (1.0f + erff(t * 0.70710678118654752f)));
        } else if constexpr (EPI == 5){     // bias -> f32 output (head)
          float t = v + g.bias[c];
          t = fminf(fmaxf(t, -1.0e4f), 1.0e4f);  // NaN-scrub for diagnosability
          g.Cf[r * (long)g.ldc + c] = t;
        } else {                            // bias + pos_emb (chunk rows batch-aligned)
          float val = v + g.bias[c] + g.pose[(long)(r & 1023) * 768 + c];
          g.C[r * (long)g.ldc + c] = f2b(val);
        }
      }
    }
  }
}

static inline void glaunch(int epi, dim3 grid, const GP& g, hipStream_t stream){
  switch (epi){
    case 0: gemm_k<0><<<grid, dim3(256), 0, stream>>>(g); break;
    case 1: gemm_k<1><<<grid, dim3(256), 0, stream>>>(g); break;
    case 2: gemm_k<2><<<grid, dim3(256), 0, stream>>>(g); break;
    case 3: gemm_k<3><<<grid, dim3(256), 0, stream>>>(g); break;
    case 4: gemm_k<4><<<grid, dim3(256), 0, stream>>>(g); break;
    case 5: gemm_k<5><<<grid, dim3(256), 0, stream>>>(g); break;
    default: gemm_k<6><<<grid, dim3(256), 0, stream>>>(g); break;
  }
}

extern "C" void kernel_launch(void* const* d_in, const int* in_sizes, int n_in,
                              void* d_out, int out_size, void* d_ws, size_t ws_size,
                              hipStream_t stream){
  (void)in_sizes; (void)n_in; (void)out_size;
  const float* patches = (const float*)d_in[0];
  const void*  mask    = d_in[1];
  const float* mtok    = (const float*)d_in[2];
  const float* patch_w = (const float*)d_in[3];
  const float* patch_b = (const float*)d_in[4];
  const float* pos_emb = (const float*)d_in[5];
  const float* rel_b   = (const float*)d_in[6];
  const float* in_w    = (const float*)d_in[7];
  const float* in_b    = (const float*)d_in[8];
  const float* attn_ow = (const float*)d_in[9];
  const float* attn_ob = (const float*)d_in[10];
  const float* ln1_s   = (const float*)d_in[11];
  const float* ln1_b   = (const float*)d_in[12];
  const float* ffn_w1  = (const float*)d_in[13];
  const float* ffn_b1  = (const float*)d_in[14];
  const float* ffn_w2  = (const float*)d_in[15];
  const float* ffn_b2  = (const float*)d_in[16];
  const float* ln2_s   = (const float*)d_in[17];
  const float* ln2_b   = (const float*)d_in[18];
  const float* head_w  = (const float*)d_in[19];
  const float* head_b  = (const float*)d_in[20];

  // ws: mode | X | WA | WB2 | S-chunks
  char* ws = (char*)d_ws;
  int* mode = (int*)ws;
  u16* X   = (u16*)(ws + 256);
  u16* WA  = X + 4096L * 768;            // up to 3072*768 bf16 (4.72MB)
  u16* WB2 = WA + 3072L * 768;           // up to 768*3072 bf16 (4.72MB)
  u16* S   = WB2 + 3072L * 768;
  long sbytes = (long)ws_size - ((char*)S - ws);
  int CH = (int)(sbytes / 2097152L);
  if (CH < 1) CH = 1;
  if (CH > 12) CH = 12;

  // d_out doubles as bf16 scratch (u16 view) until the final head GEMM
  u16*   dout16 = (u16*)d_out;
  float* doutf  = (float*)d_out;
  u16* QKb = dout16;                 // [1024,1536]
  u16* VTb = dout16 + 1572864;       // [768,1024]
  u16* Ob  = dout16 + 2359296;       // [1024,768]
  u16* XRb = dout16 + 3145728;       // [1024,768]
  u16* HBc = dout16;                 // [1024,3072]
  u16* XRc = dout16 + 3145728;       // [1024,768]
  u16* MPc = dout16;                 // [1024,768]

  detect_k<<<dim3(1), dim3(256), 0, stream>>>((const u16*)mask, mode);

  GP g;
  // patch_w -> WA, then embed + patch projection per 1024-row chunk
  wconv_k<<<dim3(576), dim3(256), 0, stream>>>(patch_w, WA);
  for (int cc = 0; cc < 4; cc++){
    embed_k<<<dim3(1024), dim3(256), 0, stream>>>(patches + (long)cc * 786432, mask, mode, mtok, MPc, cc * 1024);
    g = {};
    g.A = MPc; g.lda = 768; g.W = WA; g.ldw = 768; g.wclamp = 767;
    g.C = X + (long)cc * 786432; g.ldc = 768; g.N = 768; g.K = 768;
    g.bias = patch_b; g.pose = pos_emb;
    glaunch(6, dim3(6, 8, 1), g, stream);
  }

  for (int l = 0; l < 6; l++){
    wconv_k<<<dim3(1728), dim3(256), 0, stream>>>(in_w + (long)l * 1769472, WA);    // [2304,768]
    wconv_k<<<dim3(576),  dim3(256), 0, stream>>>(attn_ow + (long)l * 589824, WB2); // [768,768]

    for (int b = 0; b < 4; b++){
      u16* Xb = X + (long)b * 786432;
      g = {};
      g.A = Xb; g.lda = 768;
      g.W = WA; g.ldw = 768; g.wclamp = 2303;
      g.bias = in_b + (long)l * 2304;
      g.C = QKb; g.Cv = VTb;
      g.N = 2304; g.K = 768;
      glaunch(0, dim3(18, 8, 1), g, stream);

      for (int ch0 = 0; ch0 < 12; ch0 += CH){
        int zc = (12 - ch0 < CH) ? (12 - ch0) : CH;
        // scores = Q K^T * 0.125 + rel_bias
        g = {};
        g.A = QKb + ch0 * 64; g.lda = 1536; g.sAz = 64;
        g.W = QKb + 768 + ch0 * 64; g.ldw = 1536; g.sWz = 64; g.wclamp = 1023;
        g.C = S; g.sCz = 1048576;
        g.N = 1024; g.K = 64;
        g.relb = rel_b; g.scale = 0.125f;
        glaunch(1, dim3(8, 8, zc), g, stream);
        softmax_k<<<dim3(zc * 256), dim3(256), 0, stream>>>(S);
        // O[:, head] = P @ V
        g = {};
        g.A = S; g.lda = 1024; g.sAz = 1048576;
        g.W = VTb + ch0 * 65536; g.ldw = 1024; g.sWz = 65536; g.wclamp = 63;
        g.C = Ob; g.zBase = ch0;
        g.N = 64; g.K = 1024;
        glaunch(2, dim3(1, 8, zc), g, stream);
      }

      // o-projection + residual, then LN1
      g = {};
      g.A = Ob; g.lda = 768;
      g.W = WB2; g.ldw = 768; g.wclamp = 767;
      g.bias = attn_ob + (long)l * 768; g.resid = Xb;
      g.C = XRb; g.ldc = 768; g.N = 768; g.K = 768;
      glaunch(3, dim3(6, 8, 1), g, stream);
      ln_k<<<dim3(1024), dim3(256), 0, stream>>>(XRb, Xb, ln1_s + l * 768, ln1_b + l * 768);
    }

    wconv_k<<<dim3(2304), dim3(256), 0, stream>>>(ffn_w1 + (long)l * 2359296, WA);  // [3072,768]
    wconv_k<<<dim3(2304), dim3(256), 0, stream>>>(ffn_w2 + (long)l * 2359296, WB2); // [768,3072]

    for (int cc = 0; cc < 4; cc++){
      u16* Xc = X + (long)cc * 786432;
      g = {};
      g.A = Xc; g.lda = 768;
      g.W = WA; g.ldw = 768; g.wclamp = 3071;
      g.bias = ffn_b1 + (long)l * 3072;
      g.C = HBc; g.ldc = 3072; g.N = 3072; g.K = 768;
      glaunch(4, dim3(24, 8, 1), g, stream);

      g = {};
      g.A = HBc; g.lda = 3072;
      g.W = WB2; g.ldw = 3072; g.wclamp = 767;
      g.bias = ffn_b2 + (long)l * 768; g.resid = Xc;
      g.C = XRc; g.ldc = 768; g.N = 768; g.K = 3072;
      glaunch(3, dim3(6, 8, 1), g, stream);
      ln_k<<<dim3(1024), dim3(256), 0, stream>>>(XRc, Xc, ln2_s + l * 768, ln2_b + l * 768);
    }
  }

  // head: logits (f32) -> d_out; reads only X (ws) + WA
  wconv_k<<<dim3(768), dim3(256), 0, stream>>>(head_w, WA);                         // [1024,768]
  g = {};
  g.A = X; g.lda = 768;
  g.W = WA; g.ldw = 768; g.wclamp = 1023;
  g.bias = head_b;
  g.Cf = doutf; g.ldc = 1024; g.N = 1024; g.K = 768;
  glaunch(5, dim3(8, 32, 1), g, stream);
  maskout_k<<<dim3(16), dim3(256), 0, stream>>>(mask, mode, doutf + 4194304);
}

// Round 5
// 2224.649 us; speedup vs baseline: 2.6544x; 2.6544x over previous
//
#include <hip/hip_runtime.h>
#include <hip/hip_bf16.h>
#include <stdint.h>

// StackedContextViT forward, MI355X gfx950. ALL inputs/outputs are FLOAT32.
// Internal: bf16 storage + bf16 MFMA, f32 accumulate, f32 epilogue math.
// B=4 N=1024 PD=768 D=768 H=12 HD=64 L=6 F=3072 V=1024 G=32
// ws base (known safe, 15.73MB): [0]mode | X bf16[4096,768] | WA | WB
// ws extra (if >=25.2MB): QK[4096,1536] | VT[48*64,1024] | O[4096,768]  (attn)
//                         H[4096,3072]                                  (ffn, aliased)
// d_out (16.79MB) is scratch until the head GEMM writes f32 logits.

#define BM 128
#define BN 128
#define BK 32

using u16 = unsigned short;
typedef __attribute__((ext_vector_type(8))) short short8;
typedef __attribute__((ext_vector_type(4))) float f32x4;

#define GPTR(p) ((const __attribute__((address_space(1))) void*)(p))
#define LPTR(p) ((__attribute__((address_space(3))) void*)(p))

__device__ __forceinline__ float b2f(u16 u){
  union { unsigned int i; float f; } x; x.i = ((unsigned int)u) << 16; return x.f;
}
__device__ __forceinline__ u16 f2b(float f){
  f = fminf(fmaxf(f, -448.0f), 448.0f);
  union { float f; unsigned int i; } x; x.f = f;
  unsigned int r = x.i + 0x7FFFu + ((x.i >> 16) & 1u);
  return (u16)(r >> 16);
}

// ---- mask dtype detection: 0=u8 bool, 1=bf16, 2=f32, 3=i32 ----
__global__ __launch_bounds__(256) void detect_k(const u16* __restrict__ mk, int* __restrict__ mode){
  __shared__ int f[3];
  int tid = threadIdx.x;
  if (tid < 3) f[tid] = 0;
  __syncthreads();
  for (int i = tid; i < 2048; i += 256){
    u16 u = mk[i];
    if (u == 256 || u == 257) atomicOr(&f[0], 1);
    if (u == 0x3F80){ if ((i & 1) == 0) atomicOr(&f[1], 1); else atomicOr(&f[2], 1); }
  }
  __syncthreads();
  if (tid == 0){
    int m;
    if (f[0]) m = 0;
    else if (f[1]) m = 1;
    else if (f[2]) m = 2;
    else m = 3;
    *mode = m;
  }
}

__device__ __forceinline__ bool mask_at(const void* mk, int mode, int i){
  if (mode == 0) return ((const unsigned char*)mk)[i] != 0;
  if (mode == 1) return ((const u16*)mk)[i] != 0;
  if (mode == 2) return ((const float*)mk)[i] != 0.0f;
  return ((const int*)mk)[i] != 0;
}

// ---- f32 weight -> bf16 staging ----
__global__ __launch_bounds__(256) void wconv_k(const float* __restrict__ src, u16* __restrict__ dst){
  long i = ((long)blockIdx.x * 256 + threadIdx.x) * 4;
  float4 v = *(const float4*)(src + i);
  dst[i]     = f2b(v.x);
  dst[i + 1] = f2b(v.y);
  dst[i + 2] = f2b(v.z);
  dst[i + 3] = f2b(v.w);
}

// ---- masked-patch select + f32->bf16 (full 4096 rows) ----
__global__ __launch_bounds__(256) void embed_k(const float* __restrict__ patches, const void* __restrict__ mask,
                                               const int* __restrict__ mode, const float* __restrict__ mtok,
                                               u16* __restrict__ MP){
  int row = blockIdx.x;
  bool m = mask_at(mask, *mode, row);
  int tid = threadIdx.x;
  long base = (long)row * 768;
  #pragma unroll
  for (int i = 0; i < 3; i++){
    int p = tid + i * 256;
    MP[base + p] = f2b(m ? mtok[p] : patches[base + p]);
  }
}

// ---- mask echo (output #2, f32 0/1) ----
__global__ __launch_bounds__(256) void maskout_k(const void* __restrict__ mask, const int* __restrict__ mode,
                                                 float* __restrict__ out){
  int i = blockIdx.x * 256 + threadIdx.x;
  out[i] = mask_at(mask, *mode, i) ? 1.0f : 0.0f;
}

// ---- layernorm over D=768 (bf16 in/out, f32 params+math) ----
__global__ __launch_bounds__(256) void ln_k(const u16* __restrict__ XR, u16* __restrict__ X,
                                            const float* __restrict__ s, const float* __restrict__ b){
  int row = blockIdx.x;
  int tid = threadIdx.x;
  const u16* xr = XR + (long)row * 768;
  float v0 = b2f(xr[tid]), v1 = b2f(xr[tid + 256]), v2 = b2f(xr[tid + 512]);
  float sum = v0 + v1 + v2, sq = v0 * v0 + v1 * v1 + v2 * v2;
  #pragma unroll
  for (int off = 32; off; off >>= 1){ sum += __shfl_xor(sum, off); sq += __shfl_xor(sq, off); }
  __shared__ float ls[4], lq[4];
  int wave = tid >> 6, lane = tid & 63;
  if (lane == 0){ ls[wave] = sum; lq[wave] = sq; }
  __syncthreads();
  sum = ls[0] + ls[1] + ls[2] + ls[3];
  sq  = lq[0] + lq[1] + lq[2] + lq[3];
  float mu = sum * (1.0f / 768.0f);
  float var = fmaxf(sq * (1.0f / 768.0f) - mu * mu, 0.0f);
  float rs = rsqrtf(var + 1e-5f);
  u16* xo = X + (long)row * 768;
  xo[tid]       = f2b((v0 - mu) * rs * s[tid]       + b[tid]);
  xo[tid + 256] = f2b((v1 - mu) * rs * s[tid + 256] + b[tid + 256]);
  xo[tid + 512] = f2b((v2 - mu) * rs * s[tid + 512] + b[tid + 512]);
}

// ---- softmax over rows of 1024 (in place, bf16), one wave per row ----
__global__ __launch_bounds__(256) void softmax_k(u16* __restrict__ S){
  long row = (long)blockIdx.x * 4 + (threadIdx.x >> 6);
  u16* p = S + row * 1024;
  int lane = threadIdx.x & 63;
  float v[16]; float mx = -1e30f;
  #pragma unroll
  for (int i = 0; i < 16; i++){ v[i] = b2f(p[lane + i * 64]); mx = fmaxf(mx, v[i]); }
  #pragma unroll
  for (int off = 32; off; off >>= 1) mx = fmaxf(mx, __shfl_xor(mx, off));
  float sum = 0.0f;
  #pragma unroll
  for (int i = 0; i < 16; i++){ v[i] = __expf(v[i] - mx); sum += v[i]; }
  #pragma unroll
  for (int off = 32; off; off >>= 1) sum += __shfl_xor(sum, off);
  float inv = 1.0f / sum;
  #pragma unroll
  for (int i = 0; i < 16; i++) p[lane + i * 64] = f2b(v[i] * inv);
}

// ---- generic bf16 MFMA GEMM: C = A[.,K] * W[N,K]^T (+ epilogue) ----
// EPI: 0=qkv (QK natural ldc=1536, V -> VT per-head-transposed),
//      1=scores (A/W derived per head from zBase+z; *scale + f32 rel bias),
//      2=pv (O row = bg*1024+r, col = h*64+c), 3=bias+resid, 4=bias+gelu,
//      5=bias -> f32 out, 6=bias+posemb
struct GP {
  const u16* A; const u16* W; u16* C; float* Cf;
  const float* bias; const float* relb; const float* pose;
  const u16* resid;
  u16* Cv;
  long sAz, sWz, sCz;
  int lda, ldw, ldc;
  int N, K;
  int wclamp, zBase;
  float scale;
};

template<int EPI>
__global__ __launch_bounds__(256)
void gemm_k(GP g){
  __shared__ __align__(16) u16 As[BM * BK];
  __shared__ __align__(16) u16 Bs[BN * BK];
  const int tid  = threadIdx.x;
  const int wave = tid >> 6, lane = tid & 63;
  const int quad = lane >> 4, l16 = lane & 15;
  const int wm = wave >> 1, wn = wave & 1;
  const int m0 = blockIdx.y * BM, n0 = blockIdx.x * BN;
  const int z = blockIdx.z;

  const u16* Ab;
  const u16* Wb;
  if constexpr (EPI == 1){
    // per-head Q/K bases inside QK[rows,1536]: Q cols h*64, K cols 768+h*64
    int hh = g.zBase + z;
    int b = hh / 12, h = hh - b * 12;
    Ab = g.A + (long)b * 1572864 + h * 64;
    Wb = Ab + 768;
  } else {
    Ab = g.A + (long)z * g.sAz;
    Wb = g.W + (long)z * g.sWz;
  }

  f32x4 acc[4][4];
  #pragma unroll
  for (int i = 0; i < 4; i++)
    #pragma unroll
    for (int j = 0; j < 4; j++) acc[i][j] = (f32x4){0.f, 0.f, 0.f, 0.f};

  const int c0 = wave * 64 + lane;
  const int c1 = c0 + 256;
  const u16* a0 = Ab + (long)(m0 + (c0 >> 2)) * g.lda + (c0 & 3) * 8;
  const u16* a1 = Ab + (long)(m0 + (c1 >> 2)) * g.lda + (c1 & 3) * 8;
  const u16* w0 = Wb + (long)min(n0 + (c0 >> 2), g.wclamp) * g.ldw + (c0 & 3) * 8;
  const u16* w1 = Wb + (long)min(n0 + (c1 >> 2), g.wclamp) * g.ldw + (c1 & 3) * 8;
  u16* asb0 = As + (wave * 64) * 8;
  u16* asb1 = As + (256 + wave * 64) * 8;
  u16* bsb0 = Bs + (wave * 64) * 8;
  u16* bsb1 = Bs + (256 + wave * 64) * 8;

  for (int kt = 0; kt < g.K; kt += BK){
    __builtin_amdgcn_global_load_lds(GPTR(a0 + kt), LPTR(asb0), 16, 0, 0);
    __builtin_amdgcn_global_load_lds(GPTR(a1 + kt), LPTR(asb1), 16, 0, 0);
    __builtin_amdgcn_global_load_lds(GPTR(w0 + kt), LPTR(bsb0), 16, 0, 0);
    __builtin_amdgcn_global_load_lds(GPTR(w1 + kt), LPTR(bsb1), 16, 0, 0);
    __syncthreads();
    short8 af[4], bf[4];
    #pragma unroll
    for (int i = 0; i < 4; i++){
      af[i] = *(const short8*)&As[(wm * 64 + i * 16 + l16) * BK + quad * 8];
      bf[i] = *(const short8*)&Bs[(wn * 64 + i * 16 + l16) * BK + quad * 8];
    }
    #pragma unroll
    for (int i = 0; i < 4; i++)
      #pragma unroll
      for (int j = 0; j < 4; j++)
        acc[i][j] = __builtin_amdgcn_mfma_f32_16x16x32_bf16(af[i], bf[j], acc[i][j], 0, 0, 0);
    __syncthreads();
  }

  // epilogue: C/D layout col=lane&15, row=quad*4+reg
  #pragma unroll
  for (int i = 0; i < 4; i++){
    #pragma unroll
    for (int j = 0; j < 4; j++){
      #pragma unroll
      for (int rr = 0; rr < 4; rr++){
        const long r = (long)m0 + wm * 64 + i * 16 + quad * 4 + rr;
        const int  c = n0 + wn * 64 + j * 16 + l16;
        if (c >= g.N) continue;
        float v = acc[i][j][rr];
        if constexpr (EPI == 0){            // qkv: QK natural, V transposed per head
          u16 o = f2b(v + g.bias[c]);
          if (c < 1536) g.C[r * 1536 + c] = o;
          else {
            int c2 = c - 1536;
            int hh = ((int)(r >> 10)) * 12 + (c2 >> 6);
            g.Cv[((long)hh * 64 + (c2 & 63)) * 1024 + (r & 1023)] = o;
          }
        } else if constexpr (EPI == 1){     // scores: *scale + f32 Swin rel-bias
          const int rq = (int)r;
          const int ir = (rq >> 5) - (c >> 5) + 31;
          const int ic = (rq & 31) - (c & 31) + 31;
          float val = v * g.scale + g.relb[ir * 63 + ic];
          (g.C + (long)z * g.sCz)[(long)rq * 1024 + c] = f2b(val);
        } else if constexpr (EPI == 2){     // pv -> O[bg*1024+r][h*64+c]
          int hh = g.zBase + z;
          int bg = hh / 12, h = hh - bg * 12;
          g.C[((long)bg * 1024 + r) * 768 + h * 64 + c] = f2b(v);
        } else if constexpr (EPI == 3){     // bias + residual
          long o = r * (long)g.ldc + c;
          g.C[o] = f2b(v + g.bias[c] + b2f(g.resid[o]));
        } else if constexpr (EPI == 4){     // bias + exact gelu
          float t = v + g.bias[c];
          g.C[r * (long)g.ldc + c] = f2b(0.5f * t * (1.0f + erff(t * 0.70710678118654752f)));
        } else if constexpr (EPI == 5){     // bias -> f32 output (head)
          float t = v + g.bias[c];
          t = fminf(fmaxf(t, -1.0e4f), 1.0e4f);
          g.Cf[r * (long)g.ldc + c] = t;
        } else {                            // bias + pos_emb
          float val = v + g.bias[c] + g.pose[(long)(r & 1023) * 768 + c];
          g.C[r * (long)g.ldc + c] = f2b(val);
        }
      }
    }
  }
}

static inline void glaunch(int epi, dim3 grid, const GP& g, hipStream_t stream){
  switch (epi){
    case 0: gemm_k<0><<<grid, dim3(256), 0, stream>>>(g); break;
    case 1: gemm_k<1><<<grid, dim3(256), 0, stream>>>(g); break;
    case 2: gemm_k<2><<<grid, dim3(256), 0, stream>>>(g); break;
    case 3: gemm_k<3><<<grid, dim3(256), 0, stream>>>(g); break;
    case 4: gemm_k<4><<<grid, dim3(256), 0, stream>>>(g); break;
    case 5: gemm_k<5><<<grid, dim3(256), 0, stream>>>(g); break;
    default: gemm_k<6><<<grid, dim3(256), 0, stream>>>(g); break;
  }
}

extern "C" void kernel_launch(void* const* d_in, const int* in_sizes, int n_in,
                              void* d_out, int out_size, void* d_ws, size_t ws_size,
                              hipStream_t stream){
  (void)in_sizes; (void)n_in; (void)out_size;
  const float* patches = (const float*)d_in[0];
  const void*  mask    = d_in[1];
  const float* mtok    = (const float*)d_in[2];
  const float* patch_w = (const float*)d_in[3];
  const float* patch_b = (const float*)d_in[4];
  const float* pos_emb = (const float*)d_in[5];
  const float* rel_b   = (const float*)d_in[6];
  const float* in_w    = (const float*)d_in[7];
  const float* in_b    = (const float*)d_in[8];
  const float* attn_ow = (const float*)d_in[9];
  const float* attn_ob = (const float*)d_in[10];
  const float* ln1_s   = (const float*)d_in[11];
  const float* ln1_b   = (const float*)d_in[12];
  const float* ffn_w1  = (const float*)d_in[13];
  const float* ffn_b1  = (const float*)d_in[14];
  const float* ffn_w2  = (const float*)d_in[15];
  const float* ffn_b2  = (const float*)d_in[16];
  const float* ln2_s   = (const float*)d_in[17];
  const float* ln2_b   = (const float*)d_in[18];
  const float* head_w  = (const float*)d_in[19];
  const float* head_b  = (const float*)d_in[20];

  // ws base layout (known safe: round 4 ran with this + >=2MB)
  char* ws = (char*)d_ws;
  int* mode = (int*)ws;
  u16* X  = (u16*)(ws + 256);            // [4096,768]
  u16* WA = X + 3145728;                 // up to [3072,768]
  u16* WB = WA + 2359296;                // up to [3072,768]
  char* EX = (char*)(WB + 2359296);      // extra region
  long extra = (long)ws_size - 15728896L;
  const bool bigWs = extra >= 25165824L; // QK+VT+O (= H) fits in ws extra

  u16*   dout16 = (u16*)d_out;
  float* doutf  = (float*)d_out;

  // big-ws pointers (attention phase)
  u16* QKp = (u16*)EX;                   // [4096,1536]
  u16* VTp = QKp + 6291456;              // [48*64,1024]
  u16* Op  = VTp + 3145728;              // [4096,768]
  u16* Hp  = (u16*)EX;                   // [4096,3072] (ffn phase, aliased)
  // big-ws S placement: prefer leftover ws-extra, else d_out (8 slabs)
  long extra2 = extra - 25165824L;
  u16* Sp_big; int SCH_big;
  if (extra2 >= 4194304L){
    Sp_big = Op + 3145728;
    SCH_big = (int)(extra2 / 2097152L); if (SCH_big > 48) SCH_big = 48;
  } else {
    Sp_big = dout16; SCH_big = 8;
  }
  // small-ws pointers: S in ws extra, attention staged in d_out halves
  u16* Sp_small = (u16*)EX;
  int SCH_small = (int)(extra / 2097152L);
  if (SCH_small < 1) SCH_small = 1;
  if (SCH_small > 24) SCH_small = 24;
  u16* O16  = dout16;                    // [4096,768]
  u16* QKh  = dout16 + 3145728;          // [2048,1536]
  u16* VTh  = dout16 + 6291456;          // [24*64,1024]
  u16* XRb  = dout16 + 3145728;          // [4096,768] (after QKh/VTh dead)
  u16* Hc   = dout16;                    // [2048,3072]
  u16* XRc  = dout16 + 6291456;          // [2048,768]

  detect_k<<<dim3(1), dim3(256), 0, stream>>>((const u16*)mask, mode);

  GP g;
  // embed (MP in d_out) + patch projection -> X
  wconv_k<<<dim3(576), dim3(256), 0, stream>>>(patch_w, WA);
  embed_k<<<dim3(4096), dim3(256), 0, stream>>>(patches, mask, mode, mtok, dout16);
  g = {};
  g.A = dout16; g.lda = 768; g.W = WA; g.ldw = 768; g.wclamp = 767;
  g.C = X; g.ldc = 768; g.N = 768; g.K = 768;
  g.bias = patch_b; g.pose = pos_emb;
  glaunch(6, dim3(6, 32, 1), g, stream);

  for (int l = 0; l < 6; l++){
    wconv_k<<<dim3(1728), dim3(256), 0, stream>>>(in_w + (long)l * 1769472, WA);
    wconv_k<<<dim3(576),  dim3(256), 0, stream>>>(attn_ow + (long)l * 589824, WB);

    if (bigWs){
      // qkv full-M
      g = {};
      g.A = X; g.lda = 768; g.W = WA; g.ldw = 768; g.wclamp = 2303;
      g.bias = in_b + (long)l * 2304;
      g.C = QKp; g.Cv = VTp; g.N = 2304; g.K = 768;
      glaunch(0, dim3(18, 32, 1), g, stream);

      for (int ch0 = 0; ch0 < 48; ch0 += SCH_big){
        int zc = (48 - ch0 < SCH_big) ? (48 - ch0) : SCH_big;
        g = {};
        g.A = QKp; g.lda = 1536; g.zBase = ch0;
        g.C = Sp_big; g.sCz = 1048576; g.N = 1024; g.K = 64;
        g.relb = rel_b; g.scale = 0.125f; g.wclamp = 1023;
        glaunch(1, dim3(8, 8, zc), g, stream);
        softmax_k<<<dim3(zc * 256), dim3(256), 0, stream>>>(Sp_big);
        g = {};
        g.A = Sp_big; g.lda = 1024; g.sAz = 1048576;
        g.W = VTp + (long)ch0 * 65536; g.ldw = 1024; g.sWz = 65536; g.wclamp = 63;
        g.C = Op; g.zBase = ch0; g.N = 64; g.K = 1024;
        glaunch(2, dim3(1, 8, zc), g, stream);
      }

      // o-proj + residual -> XR(d_out), LN1 -> X
      g = {};
      g.A = Op; g.lda = 768; g.W = WB; g.ldw = 768; g.wclamp = 767;
      g.bias = attn_ob + (long)l * 768; g.resid = X;
      g.C = dout16; g.ldc = 768; g.N = 768; g.K = 768;
      glaunch(3, dim3(6, 32, 1), g, stream);
      ln_k<<<dim3(4096), dim3(256), 0, stream>>>(dout16, X, ln1_s + l * 768, ln1_b + l * 768);
    } else {
      for (int hb = 0; hb < 2; hb++){
        g = {};
        g.A = X + (long)hb * 1572864; g.lda = 768;
        g.W = WA; g.ldw = 768; g.wclamp = 2303;
        g.bias = in_b + (long)l * 2304;
        g.C = QKh; g.Cv = VTh; g.N = 2304; g.K = 768;
        glaunch(0, dim3(18, 16, 1), g, stream);

        for (int ch0 = 0; ch0 < 24; ch0 += SCH_small){
          int zc = (24 - ch0 < SCH_small) ? (24 - ch0) : SCH_small;
          g = {};
          g.A = QKh; g.lda = 1536; g.zBase = ch0;          // b local in {0,1}
          g.C = Sp_small; g.sCz = 1048576; g.N = 1024; g.K = 64;
          g.relb = rel_b; g.scale = 0.125f; g.wclamp = 1023;
          glaunch(1, dim3(8, 8, zc), g, stream);
          softmax_k<<<dim3(zc * 256), dim3(256), 0, stream>>>(Sp_small);
          g = {};
          g.A = Sp_small; g.lda = 1024; g.sAz = 1048576;
          g.W = VTh + (long)ch0 * 65536; g.ldw = 1024; g.sWz = 65536; g.wclamp = 63;
          g.C = O16; g.zBase = hb * 24 + ch0; g.N = 64; g.K = 1024;
          glaunch(2, dim3(1, 8, zc), g, stream);
        }
      }
      g = {};
      g.A = O16; g.lda = 768; g.W = WB; g.ldw = 768; g.wclamp = 767;
      g.bias = attn_ob + (long)l * 768; g.resid = X;
      g.C = XRb; g.ldc = 768; g.N = 768; g.K = 768;
      glaunch(3, dim3(6, 32, 1), g, stream);
      ln_k<<<dim3(4096), dim3(256), 0, stream>>>(XRb, X, ln1_s + l * 768, ln1_b + l * 768);
    }

    wconv_k<<<dim3(2304), dim3(256), 0, stream>>>(ffn_w1 + (long)l * 2359296, WA);
    wconv_k<<<dim3(2304), dim3(256), 0, stream>>>(ffn_w2 + (long)l * 2359296, WB);

    if (bigWs){
      g = {};
      g.A = X; g.lda = 768; g.W = WA; g.ldw = 768; g.wclamp = 3071;
      g.bias = ffn_b1 + (long)l * 3072;
      g.C = Hp; g.ldc = 3072; g.N = 3072; g.K = 768;
      glaunch(4, dim3(24, 32, 1), g, stream);
      g = {};
      g.A = Hp; g.lda = 3072; g.W = WB; g.ldw = 3072; g.wclamp = 767;
      g.bias = ffn_b2 + (long)l * 768; g.resid = X;
      g.C = dout16; g.ldc = 768; g.N = 768; g.K = 3072;
      glaunch(3, dim3(6, 32, 1), g, stream);
      ln_k<<<dim3(4096), dim3(256), 0, stream>>>(dout16, X, ln2_s + l * 768, ln2_b + l * 768);
    } else {
      for (int cc = 0; cc < 2; cc++){
        u16* Xc = X + (long)cc * 1572864;
        g = {};
        g.A = Xc; g.lda = 768; g.W = WA; g.ldw = 768; g.wclamp = 3071;
        g.bias = ffn_b1 + (long)l * 3072;
        g.C = Hc; g.ldc = 3072; g.N = 3072; g.K = 768;
        glaunch(4, dim3(24, 16, 1), g, stream);
        g = {};
        g.A = Hc; g.lda = 3072; g.W = WB; g.ldw = 3072; g.wclamp = 767;
        g.bias = ffn_b2 + (long)l * 768; g.resid = Xc;
        g.C = XRc; g.ldc = 768; g.N = 768; g.K = 3072;
        glaunch(3, dim3(6, 16, 1), g, stream);
        ln_k<<<dim3(2048), dim3(256), 0, stream>>>(XRc, Xc, ln2_s + l * 768, ln2_b + l * 768);
      }
    }
  }

  // head: logits (f32) -> d_out
  wconv_k<<<dim3(768), dim3(256), 0, stream>>>(head_w, WA);
  g = {};
  g.A = X; g.lda = 768; g.W = WA; g.ldw = 768; g.wclamp = 1023;
  g.bias = head_b;
  g.Cf = doutf; g.ldc = 1024; g.N = 1024; g.K = 768;
  glaunch(5, dim3(8, 32, 1), g, stream);
  maskout_k<<<dim3(16), dim3(256), 0, stream>>>(mask, mode, doutf + 4194304);
}